// Round 2
// baseline (957.667 us; speedup 1.0000x reference)
//
#include <hip/hip_runtime.h>

typedef __attribute__((ext_vector_type(4))) float f32x4;
typedef __attribute__((ext_vector_type(8))) short bf16x8;

#define BM 128
#define BN 128
#define BK 64
#define NTHREADS 256
#define M_TOTAL 32768
#define N_TOTAL 1024
#define K_TOTAL 1024

__device__ __forceinline__ ushort f2bf(float f) {
  // fp32 -> bf16 round-to-nearest-even (inputs are finite)
  uint u = __builtin_bit_cast(uint, f);
  return (ushort)((u + 0x7FFFu + ((u >> 16) & 1u)) >> 16);
}

__global__ __launch_bounds__(NTHREADS, 2) void qlin_gemm(
    const float* __restrict__ X, const float* __restrict__ Rm,
    const float* __restrict__ Im, const float* __restrict__ Jm,
    const float* __restrict__ Km, const float* __restrict__ bias,
    float* __restrict__ Y)
{
  // 2048 blocks = 256 m-blocks x 8 n-blocks. XCD-bijective swizzle (2048%8==0),
  // n fastest within an XCD chunk so 8 n-blocks share each A-panel via L2.
  const int nwg = (M_TOTAL / BM) * (N_TOTAL / BN);
  const int per = nwg >> 3;
  const int bid = (int)blockIdx.x;
  const int swz = (bid & 7) * per + (bid >> 3);
  const int mblk = swz >> 3;
  const int nblk = swz & 7;
  const int m0 = mblk * BM;
  const int n0 = nblk * BN;

  const int tid = (int)threadIdx.x;
  const int lane = tid & 63;
  const int wave = tid >> 6;
  const int wm = (wave >> 1) << 6;  // wave row origin: 0/64
  const int wn = (wave & 1) << 6;   // wave col origin: 0/64

  __shared__ __align__(16) ushort smA[BM * BK];
  __shared__ __align__(16) ushort smB[BN * BK];
  char* const cA = (char*)smA;
  char* const cB = (char*)smB;

  // Quaternion block structure: W[o,i] = sign(a,b) * S[a^b][o&255, i&255]
  // a = o>>8, b = i>>8 ; src index is XOR; sign mask bit (a*4+b) of 0x284E.
  const int a_idx = n0 >> 8;
  const int o_src = n0 & 255;

  // staging: 4 chunks of 8 elems per thread; chunk c = tid + 256*cc
  int srow[4], sk0[4], sboff[4];
#pragma unroll
  for (int cc = 0; cc < 4; ++cc) {
    const int c = tid + NTHREADS * cc;
    srow[cc] = c >> 3;            // 0..127
    sk0[cc] = (c & 7) << 3;       // 0..56
    // XOR-swizzled byte offset (T2): row*128 + (k_bytes ^ ((row&7)<<4))
    sboff[cc] = srow[cc] * (BK * 2) + ((sk0[cc] * 2) ^ ((srow[cc] & 7) << 4));
  }

  f32x4 rA[8], rB[8];
  f32x4 acc[4][4];
#pragma unroll
  for (int i = 0; i < 4; ++i)
#pragma unroll
    for (int j = 0; j < 4; ++j) acc[i][j] = (f32x4)(0.0f);

  auto issue = [&](int kk0) {
    const int bsel = kk0 >> 8;
    const int si = a_idx ^ bsel;
    const float* Bsrc = (si == 0) ? Rm : (si == 1) ? Im : (si == 2) ? Jm : Km;
    const int kloc = kk0 & 255;
#pragma unroll
    for (int cc = 0; cc < 4; ++cc) {
      const float* pa = X + (size_t)(m0 + srow[cc]) * K_TOTAL + (kk0 + sk0[cc]);
      rA[2 * cc] = *(const f32x4*)pa;
      rA[2 * cc + 1] = *(const f32x4*)(pa + 4);
      const float* pb = Bsrc + (o_src + srow[cc]) * 256 + (kloc + sk0[cc]);
      rB[2 * cc] = *(const f32x4*)pb;
      rB[2 * cc + 1] = *(const f32x4*)(pb + 4);
    }
  };

  auto commit = [&](int kk0) {
    const int bsel = kk0 >> 8;
    const uint neg = (0x284Eu >> ((a_idx << 2) | bsel)) & 1u;
    const float sgn = neg ? -1.0f : 1.0f;
#pragma unroll
    for (int cc = 0; cc < 4; ++cc) {
      bf16x8 va, vb;
#pragma unroll
      for (int e = 0; e < 4; ++e) {
        va[e] = (short)f2bf(rA[2 * cc][e]);
        va[4 + e] = (short)f2bf(rA[2 * cc + 1][e]);
        vb[e] = (short)f2bf(sgn * rB[2 * cc][e]);
        vb[4 + e] = (short)f2bf(sgn * rB[2 * cc + 1][e]);
      }
      *(bf16x8*)(cA + sboff[cc]) = va;
      *(bf16x8*)(cB + sboff[cc]) = vb;
    }
  };

  const int frow_a0 = wm + (lane & 15);
  const int frow_b0 = wn + (lane & 15);
  const int fkb = (lane >> 4) << 4;  // 0,16,32,48 byte k-slot

  auto compute = [&]() {
#pragma unroll
    for (int ks = 0; ks < 2; ++ks) {
      const int kb = (ks << 6) + fkb;
      bf16x8 af[4], bfr[4];
#pragma unroll
      for (int mi = 0; mi < 4; ++mi) {
        const int row = frow_a0 + (mi << 4);
        af[mi] = *(const bf16x8*)(cA + row * (BK * 2) + (kb ^ ((row & 7) << 4)));
      }
#pragma unroll
      for (int ni = 0; ni < 4; ++ni) {
        const int row = frow_b0 + (ni << 4);
        bfr[ni] = *(const bf16x8*)(cB + row * (BK * 2) + (kb ^ ((row & 7) << 4)));
      }
#pragma unroll
      for (int mi = 0; mi < 4; ++mi)
#pragma unroll
        for (int ni = 0; ni < 4; ++ni)
          acc[mi][ni] = __builtin_amdgcn_mfma_f32_16x16x32_bf16(
              af[mi], bfr[ni], acc[mi][ni], 0, 0, 0);
    }
  };

  issue(0);
#pragma unroll 1
  for (int kk0 = 0; kk0 < K_TOTAL; kk0 += BK) {
    __syncthreads();             // previous compute done reading LDS
    commit(kk0);                 // cvt + swizzled ds_write
    __syncthreads();
    if (kk0 + BK < K_TOTAL) issue(kk0 + BK);  // prefetch overlaps MFMA
    compute();
  }

  // epilogue: C/D layout col = lane&15, row = (lane>>4)*4 + reg  [m89-verified]
#pragma unroll
  for (int ni = 0; ni < 4; ++ni) {
    const int col = n0 + wn + (ni << 4) + (lane & 15);
    const float bv = bias[col];
#pragma unroll
    for (int mi = 0; mi < 4; ++mi) {
      const int r0 = m0 + wm + (mi << 4) + ((lane >> 4) << 2);
#pragma unroll
      for (int j = 0; j < 4; ++j)
        Y[(size_t)(r0 + j) * N_TOTAL + col] = acc[mi][ni][j] + bv;
    }
  }
}

extern "C" void kernel_launch(void* const* d_in, const int* in_sizes, int n_in,
                              void* d_out, int out_size, void* d_ws, size_t ws_size,
                              hipStream_t stream) {
  const float* X = (const float*)d_in[0];
  const float* Rm = (const float*)d_in[1];
  const float* Im = (const float*)d_in[2];
  const float* Jm = (const float*)d_in[3];
  const float* Km = (const float*)d_in[4];
  const float* bias = (const float*)d_in[5];
  float* Y = (float*)d_out;
  dim3 grid((M_TOTAL / BM) * (N_TOTAL / BN));
  qlin_gemm<<<grid, dim3(NTHREADS), 0, stream>>>(X, Rm, Im, Jm, Km, bias, Y);
}

// Round 4
// 125.421 us; speedup vs baseline: 7.6356x; 7.6356x over previous
//
#include <hip/hip_runtime.h>
#include <hip/hip_bf16.h>

typedef __attribute__((ext_vector_type(4))) float f32x4;
typedef __attribute__((ext_vector_type(4))) uint u32x4;
typedef __attribute__((ext_vector_type(8))) short bf16x8;

#define BM 128
#define BN 128
#define BK 64
#define NTHREADS 256
#define M_TOTAL 32768
#define N_TOTAL 1024
#define K_TOTAL 1024

__device__ __forceinline__ uint pk2(float a, float b) {
  __hip_bfloat162 h = __float22bfloat162_rn(make_float2(a, b));  // v_cvt_pk_bf16_f32
  uint u;
  __builtin_memcpy(&u, &h, 4);
  return u;
}

__global__ __launch_bounds__(NTHREADS, 2) void qlin_gemm(
    const float* __restrict__ X, const float* __restrict__ Rm,
    const float* __restrict__ Im, const float* __restrict__ Jm,
    const float* __restrict__ Km, const float* __restrict__ bias,
    float* __restrict__ Y)
{
  // 2048 blocks = 256 m-blocks x 8 n-blocks. XCD-bijective swizzle (2048%8==0),
  // n fastest within an XCD chunk so 8 n-blocks share each A-panel via L2.
  const int per = ((M_TOTAL / BM) * (N_TOTAL / BN)) >> 3;
  const int bid = (int)blockIdx.x;
  const int swz = (bid & 7) * per + (bid >> 3);
  const int m0 = (swz >> 3) * BM;
  const int n0 = (swz & 7) * BN;

  const int tid = (int)threadIdx.x;
  const int lane = tid & 63;
  const int wave = tid >> 6;
  const int wm = (wave >> 1) << 6;  // wave row origin: 0/64
  const int wn = (wave & 1) << 6;   // wave col origin: 0/64

  __shared__ __align__(16) ushort smA[BM * BK];
  __shared__ __align__(16) ushort smB[BN * BK];
  char* const cA = (char*)smA;
  char* const cB = (char*)smB;

  // Quaternion block structure: W[o,i] = sign(a,b) * S[a^b][o&255, i&255]
  // a = o>>8, b = i>>8 ; src index is XOR; sign mask bit (a*4+b) of 0x284E.
  const int a_idx = n0 >> 8;
  const int o_src = n0 & 255;

  // staging coords: thread stages 4 chunks of 8 elems; chunk cc -> row r0+32*cc,
  // elem-k k0 (same for all chunks). Swizzle XOR term depends only on r0&7.
  const int r0 = tid >> 3;            // 0..31
  const int k0 = (tid & 7) << 3;      // 0..56 (elems)
  const int sbase = r0 * (BK * 2) + ((k0 * 2) ^ ((r0 & 7) << 4));  // + 4096*cc

  // NO lambdas anywhere: by-ref capture of these arrays defeats SROA -> scratch
  // (round-2 evidence: VGPR_Count=52, 2.24 GB scratch writes). Static idx only.
  f32x4 rA[8], rB[8];
  f32x4 acc[4][4];
#pragma unroll
  for (int i = 0; i < 4; ++i)
#pragma unroll
    for (int j = 0; j < 4; ++j) acc[i][j] = (f32x4)(0.0f);

  const int frow_a0 = wm + (lane & 15);
  const int frow_b0 = wn + (lane & 15);
  const int fkb = (lane >> 4) << 4;  // 0,16,32,48 byte k-slot

  // ---- prologue: issue K-step 0 ----
  {
    const float* Bsrc = (a_idx == 0) ? Rm : (a_idx == 1) ? Im : (a_idx == 2) ? Jm : Km;
#pragma unroll
    for (int cc = 0; cc < 4; ++cc) {
      const float* pa = X + (size_t)(m0 + r0 + 32 * cc) * K_TOTAL + k0;
      rA[2 * cc] = *(const f32x4*)pa;
      rA[2 * cc + 1] = *(const f32x4*)(pa + 4);
      const float* pb = Bsrc + (o_src + r0 + 32 * cc) * 256 + k0;
      rB[2 * cc] = *(const f32x4*)pb;
      rB[2 * cc + 1] = *(const f32x4*)(pb + 4);
    }
  }

#pragma unroll 1
  for (int kk0 = 0; kk0 < K_TOTAL; kk0 += BK) {
    __syncthreads();  // previous compute done reading LDS

    // ---- commit: cvt_pk + swizzled ds_write (sign via uniform branch) ----
    {
      const int bsel = kk0 >> 8;
      const uint neg = (0x284Eu >> ((a_idx << 2) | bsel)) & 1u;
#pragma unroll
      for (int cc = 0; cc < 4; ++cc) {
        u32x4 va;
        va[0] = pk2(rA[2 * cc][0], rA[2 * cc][1]);
        va[1] = pk2(rA[2 * cc][2], rA[2 * cc][3]);
        va[2] = pk2(rA[2 * cc + 1][0], rA[2 * cc + 1][1]);
        va[3] = pk2(rA[2 * cc + 1][2], rA[2 * cc + 1][3]);
        *(u32x4*)(cA + sbase + 4096 * cc) = va;
      }
      if (neg) {
#pragma unroll
        for (int cc = 0; cc < 4; ++cc) {
          u32x4 vb;
          vb[0] = pk2(-rB[2 * cc][0], -rB[2 * cc][1]);
          vb[1] = pk2(-rB[2 * cc][2], -rB[2 * cc][3]);
          vb[2] = pk2(-rB[2 * cc + 1][0], -rB[2 * cc + 1][1]);
          vb[3] = pk2(-rB[2 * cc + 1][2], -rB[2 * cc + 1][3]);
          *(u32x4*)(cB + sbase + 4096 * cc) = vb;
        }
      } else {
#pragma unroll
        for (int cc = 0; cc < 4; ++cc) {
          u32x4 vb;
          vb[0] = pk2(rB[2 * cc][0], rB[2 * cc][1]);
          vb[1] = pk2(rB[2 * cc][2], rB[2 * cc][3]);
          vb[2] = pk2(rB[2 * cc + 1][0], rB[2 * cc + 1][1]);
          vb[3] = pk2(rB[2 * cc + 1][2], rB[2 * cc + 1][3]);
          *(u32x4*)(cB + sbase + 4096 * cc) = vb;
        }
      }
    }

    __syncthreads();  // tiles visible

    // ---- issue next K-step (global->reg, overlaps MFMA below) ----
    if (kk0 + BK < K_TOTAL) {
      const int kn = kk0 + BK;
      const int si = a_idx ^ (kn >> 8);
      const float* Bsrc = (si == 0) ? Rm : (si == 1) ? Im : (si == 2) ? Jm : Km;
      const int kloc = kn & 255;
#pragma unroll
      for (int cc = 0; cc < 4; ++cc) {
        const float* pa = X + (size_t)(m0 + r0 + 32 * cc) * K_TOTAL + kn + k0;
        rA[2 * cc] = *(const f32x4*)pa;
        rA[2 * cc + 1] = *(const f32x4*)(pa + 4);
        const float* pb = Bsrc + (o_src + r0 + 32 * cc) * 256 + kloc + k0;
        rB[2 * cc] = *(const f32x4*)pb;
        rB[2 * cc + 1] = *(const f32x4*)(pb + 4);
      }
    }

    // ---- compute: swizzled ds_read_b128 + 32x mfma_16x16x32_bf16 ----
#pragma unroll
    for (int ks = 0; ks < 2; ++ks) {
      const int kb = (ks << 6) + fkb;
      bf16x8 af[4], bfr[4];
#pragma unroll
      for (int mi = 0; mi < 4; ++mi) {
        const int row = frow_a0 + (mi << 4);
        af[mi] = *(const bf16x8*)(cA + row * (BK * 2) + (kb ^ ((row & 7) << 4)));
      }
#pragma unroll
      for (int ni = 0; ni < 4; ++ni) {
        const int row = frow_b0 + (ni << 4);
        bfr[ni] = *(const bf16x8*)(cB + row * (BK * 2) + (kb ^ ((row & 7) << 4)));
      }
#pragma unroll
      for (int mi = 0; mi < 4; ++mi)
#pragma unroll
        for (int ni = 0; ni < 4; ++ni)
          acc[mi][ni] = __builtin_amdgcn_mfma_f32_16x16x32_bf16(
              af[mi], bfr[ni], acc[mi][ni], 0, 0, 0);
    }
  }

  // epilogue: C/D layout col = lane&15, row = (lane>>4)*4 + reg  [m89-verified]
#pragma unroll
  for (int ni = 0; ni < 4; ++ni) {
    const int col = n0 + wn + (ni << 4) + (lane & 15);
    const float bv = bias[col];
#pragma unroll
    for (int mi = 0; mi < 4; ++mi) {
      const int r0e = m0 + wm + (mi << 4) + ((lane >> 4) << 2);
#pragma unroll
      for (int j = 0; j < 4; ++j)
        Y[(size_t)(r0e + j) * N_TOTAL + col] = acc[mi][ni][j] + bv;
    }
  }
}

extern "C" void kernel_launch(void* const* d_in, const int* in_sizes, int n_in,
                              void* d_out, int out_size, void* d_ws, size_t ws_size,
                              hipStream_t stream) {
  const float* X = (const float*)d_in[0];
  const float* Rm = (const float*)d_in[1];
  const float* Im = (const float*)d_in[2];
  const float* Jm = (const float*)d_in[3];
  const float* Km = (const float*)d_in[4];
  const float* bias = (const float*)d_in[5];
  float* Y = (float*)d_out;
  dim3 grid((M_TOTAL / BM) * (N_TOTAL / BN));
  qlin_gemm<<<grid, dim3(NTHREADS), 0, stream>>>(X, Rm, Im, Jm, Km, bias, Y);
}

// Round 5
// 124.321 us; speedup vs baseline: 7.7032x; 1.0088x over previous
//
#include <hip/hip_runtime.h>
#include <hip/hip_bf16.h>

typedef __attribute__((ext_vector_type(4))) float f32x4;
typedef __attribute__((ext_vector_type(4))) uint u32x4;
typedef __attribute__((ext_vector_type(8))) short bf16x8;

#define BM 128
#define BN 128
#define BK 64
#define NTHREADS 256
#define M_TOTAL 32768
#define N_TOTAL 1024
#define K_TOTAL 1024
#define NSTEPS (K_TOTAL / BK)

__device__ __forceinline__ uint pk2(float a, float b) {
  __hip_bfloat162 h = __float22bfloat162_rn(make_float2(a, b));  // v_cvt_pk_bf16_f32
  uint u;
  __builtin_memcpy(&u, &h, 4);
  return u;
}

// Macros (NOT lambdas: by-ref capture of arrays defeats SROA -> scratch;
// round-2 evidence VGPR_Count=52 + 2.24 GB scratch writes).

#define LOAD_TILE(kk) do {                                                    \
    const int si_ = a_idx ^ ((kk) >> 8);                                      \
    const float* Bsrc_ = (si_ == 0) ? Rm : (si_ == 1) ? Im                    \
                       : (si_ == 2) ? Jm : Km;                                \
    const int kloc_ = (kk) & 255;                                             \
    _Pragma("unroll")                                                         \
    for (int cc = 0; cc < 4; ++cc) {                                          \
      const float* pa_ = X + (size_t)(m0 + r0 + 32 * cc) * K_TOTAL + (kk) + k0;\
      rA[2 * cc]     = *(const f32x4*)pa_;                                    \
      rA[2 * cc + 1] = *(const f32x4*)(pa_ + 4);                              \
      const float* pb_ = Bsrc_ + (o_src + r0 + 32 * cc) * 256 + kloc_ + k0;   \
      rB[2 * cc]     = *(const f32x4*)pb_;                                    \
      rB[2 * cc + 1] = *(const f32x4*)(pb_ + 4);                              \
    }                                                                         \
  } while (0)

#define COMMIT_TILE(kk, dst) do {                                             \
    const uint neg_ = (0x284Eu >> ((a_idx << 2) | ((kk) >> 8))) & 1u;         \
    _Pragma("unroll")                                                         \
    for (int cc = 0; cc < 4; ++cc) {                                          \
      u32x4 va_;                                                              \
      va_[0] = pk2(rA[2 * cc][0], rA[2 * cc][1]);                             \
      va_[1] = pk2(rA[2 * cc][2], rA[2 * cc][3]);                             \
      va_[2] = pk2(rA[2 * cc + 1][0], rA[2 * cc + 1][1]);                     \
      va_[3] = pk2(rA[2 * cc + 1][2], rA[2 * cc + 1][3]);                     \
      *(u32x4*)((dst) + sbase + 4096 * cc) = va_;                             \
    }                                                                         \
    if (neg_) {                                                               \
      _Pragma("unroll")                                                       \
      for (int cc = 0; cc < 4; ++cc) {                                        \
        u32x4 vb_;                                                            \
        vb_[0] = pk2(-rB[2 * cc][0], -rB[2 * cc][1]);                         \
        vb_[1] = pk2(-rB[2 * cc][2], -rB[2 * cc][3]);                         \
        vb_[2] = pk2(-rB[2 * cc + 1][0], -rB[2 * cc + 1][1]);                 \
        vb_[3] = pk2(-rB[2 * cc + 1][2], -rB[2 * cc + 1][3]);                 \
        *(u32x4*)((dst) + 16384 + sbase + 4096 * cc) = vb_;                   \
      }                                                                       \
    } else {                                                                  \
      _Pragma("unroll")                                                       \
      for (int cc = 0; cc < 4; ++cc) {                                        \
        u32x4 vb_;                                                            \
        vb_[0] = pk2(rB[2 * cc][0], rB[2 * cc][1]);                           \
        vb_[1] = pk2(rB[2 * cc][2], rB[2 * cc][3]);                           \
        vb_[2] = pk2(rB[2 * cc + 1][0], rB[2 * cc + 1][1]);                   \
        vb_[3] = pk2(rB[2 * cc + 1][2], rB[2 * cc + 1][3]);                   \
        *(u32x4*)((dst) + 16384 + sbase + 4096 * cc) = vb_;                   \
      }                                                                       \
    }                                                                         \
  } while (0)

#define COMPUTE_TILE(src) do {                                                \
    _Pragma("unroll")                                                         \
    for (int ks = 0; ks < 2; ++ks) {                                          \
      const int kb_ = (ks << 6) + fkb;                                        \
      bf16x8 af_[4], bf_[4];                                                  \
      _Pragma("unroll")                                                       \
      for (int mi = 0; mi < 4; ++mi) {                                        \
        const int row_ = frow_a0 + (mi << 4);                                 \
        af_[mi] = *(const bf16x8*)((src) + row_ * (BK * 2)                    \
                                   + (kb_ ^ ((row_ & 7) << 4)));              \
      }                                                                       \
      _Pragma("unroll")                                                       \
      for (int ni = 0; ni < 4; ++ni) {                                        \
        const int row_ = frow_b0 + (ni << 4);                                 \
        bf_[ni] = *(const bf16x8*)((src) + 16384 + row_ * (BK * 2)            \
                                   + (kb_ ^ ((row_ & 7) << 4)));              \
      }                                                                       \
      _Pragma("unroll")                                                       \
      for (int mi = 0; mi < 4; ++mi)                                          \
        _Pragma("unroll")                                                     \
        for (int ni = 0; ni < 4; ++ni)                                        \
          acc[mi][ni] = __builtin_amdgcn_mfma_f32_16x16x32_bf16(              \
              af_[mi], bf_[ni], acc[mi][ni], 0, 0, 0);                        \
    }                                                                         \
  } while (0)

__global__ __launch_bounds__(NTHREADS, 2) void qlin_gemm(
    const float* __restrict__ X, const float* __restrict__ Rm,
    const float* __restrict__ Im, const float* __restrict__ Jm,
    const float* __restrict__ Km, const float* __restrict__ bias,
    float* __restrict__ Y)
{
  // 2048 blocks = 256 m-blocks x 8 n-blocks. XCD-bijective swizzle (2048%8==0),
  // n fastest within an XCD chunk so 8 n-blocks share each A-panel via L2.
  const int per = ((M_TOTAL / BM) * (N_TOTAL / BN)) >> 3;
  const int bid = (int)blockIdx.x;
  const int swz = (bid & 7) * per + (bid >> 3);
  const int m0 = (swz >> 3) * BM;
  const int n0 = (swz & 7) * BN;

  const int tid = (int)threadIdx.x;
  const int lane = tid & 63;
  const int wave = tid >> 6;
  const int wm = (wave >> 1) << 6;  // wave row origin: 0/64
  const int wn = (wave & 1) << 6;   // wave col origin: 0/64

  // Double-buffered: [buf][A|B][128*64] bf16 = 64 KB total -> 2 blocks/CU.
  __shared__ __align__(16) ushort sm[2 * 2 * BM * BK];
  char* const cS = (char*)sm;

  // Quaternion block structure: W[o,i] = sign(a,b) * S[a^b][o&255, i&255]
  // a = o>>8, b = i>>8 ; src index is XOR; sign mask bit (a*4+b) of 0x284E.
  const int a_idx = n0 >> 8;
  const int o_src = n0 & 255;

  // staging coords: thread stages 4 chunks of 8 elems; chunk cc -> row r0+32*cc.
  const int r0 = tid >> 3;        // 0..31
  const int k0 = (tid & 7) << 3;  // 0..56 (elems)
  const int sbase = r0 * (BK * 2) + ((k0 * 2) ^ ((r0 & 7) << 4));  // +4096*cc

  f32x4 rA[8], rB[8];
  f32x4 acc[4][4];
#pragma unroll
  for (int i = 0; i < 4; ++i)
#pragma unroll
    for (int j = 0; j < 4; ++j) acc[i][j] = (f32x4)(0.0f);

  const int frow_a0 = wm + (lane & 15);
  const int frow_b0 = wn + (lane & 15);
  const int fkb = (lane >> 4) << 4;  // 0,16,32,48 byte k-slot

  // ---- prologue: tile 0 into buf0, tile 1 loads in flight ----
  LOAD_TILE(0);
  COMMIT_TILE(0, cS);
  LOAD_TILE(BK);
  __syncthreads();

  // ---- main loop: ONE barrier per K-step; commit(k+1) || loads(k+2) ||
  //      compute(k) share a barrier-free region so cvt-VALU and ds_write
  //      interleave with MFMA (separate pipes). ----
#pragma unroll 1
  for (int k = 0; k < NSTEPS; ++k) {
    char* const rbuf = cS + ((k & 1) << 15);
    char* const wbuf = cS + (((k + 1) & 1) << 15);
    if (k + 1 < NSTEPS) COMMIT_TILE((k + 1) * BK, wbuf);
    if (k + 2 < NSTEPS) LOAD_TILE((k + 2) * BK);
    COMPUTE_TILE(rbuf);
    __syncthreads();
  }

  // epilogue: C/D layout col = lane&15, row = (lane>>4)*4 + reg  [m89-verified]
#pragma unroll
  for (int ni = 0; ni < 4; ++ni) {
    const int col = n0 + wn + (ni << 4) + (lane & 15);
    const float bv = bias[col];
#pragma unroll
    for (int mi = 0; mi < 4; ++mi) {
      const int r0e = m0 + wm + (mi << 4) + ((lane >> 4) << 2);
#pragma unroll
      for (int j = 0; j < 4; ++j)
        Y[(size_t)(r0e + j) * N_TOTAL + col] = acc[mi][ni][j] + bv;
    }
  }
}

extern "C" void kernel_launch(void* const* d_in, const int* in_sizes, int n_in,
                              void* d_out, int out_size, void* d_ws, size_t ws_size,
                              hipStream_t stream) {
  const float* X = (const float*)d_in[0];
  const float* Rm = (const float*)d_in[1];
  const float* Im = (const float*)d_in[2];
  const float* Jm = (const float*)d_in[3];
  const float* Km = (const float*)d_in[4];
  const float* bias = (const float*)d_in[5];
  float* Y = (float*)d_out;
  dim3 grid((M_TOTAL / BM) * (N_TOTAL / BN));
  qlin_gemm<<<grid, dim3(NTHREADS), 0, stream>>>(X, Rm, Im, Jm, Km, bias, Y);
}